// Round 11
// baseline (3640.313 us; speedup 1.0000x reference)
//
#include <hip/hip_runtime.h>
#include <hip/hip_bf16.h>

typedef __hip_bfloat16 bf16;
typedef unsigned short u16;
typedef unsigned long long u64;
using frag  = __attribute__((ext_vector_type(8))) short;   // 8 bf16
using f32x4 = __attribute__((ext_vector_type(4))) float;   // 4 fp32 acc

static constexpr int T_  = 128;
static constexpr int B_  = 512;
static constexpr int H_  = 512;
static constexpr int K_  = 512;
static constexpr int G4_ = 2048;
static constexpr int NWG = 256;

// dynamic LDS: frag-blocked weights 128KB + exchange region 16KB
static constexpr size_t W_BYTES    = 131072;
static constexpr size_t XCHG_BYTES = 16384;
static constexpr size_t SMEM_BYTES = W_BYTES + XCHG_BYTES;   // 147456 (+10KB static)

// coherent (agent-scope, L1/L2-bypassing) 16B load as 2x b64 relaxed atomics
__device__ __forceinline__ frag ld_coh(const u16* p) {
  u64 lo = __hip_atomic_load((const u64*)p,       __ATOMIC_RELAXED, __HIP_MEMORY_SCOPE_AGENT);
  u64 hi = __hip_atomic_load((const u64*)(p + 4), __ATOMIC_RELAXED, __HIP_MEMORY_SCOPE_AGENT);
  union { u64 q[2]; frag f; } u;
  u.q[0] = lo; u.q[1] = hi;
  return u.f;
}

// ---------------- setup kernels ----------------

__global__ void k_f32_to_bf16_v4(const float4* __restrict__ src,
                                 ushort4* __restrict__ dst, int n4) {
  int i = blockIdx.x * blockDim.x + threadIdx.x;
  int stride = gridDim.x * blockDim.x;
  for (; i < n4; i += stride) {
    float4 v = src[i];
    ushort4 o;
    bf16 t0 = __float2bfloat16(v.x); o.x = *reinterpret_cast<u16*>(&t0);
    bf16 t1 = __float2bfloat16(v.y); o.y = *reinterpret_cast<u16*>(&t1);
    bf16 t2 = __float2bfloat16(v.z); o.z = *reinterpret_cast<u16*>(&t2);
    bf16 t3 = __float2bfloat16(v.w); o.w = *reinterpret_cast<u16*>(&t3);
    dst[i] = o;
  }
}

__global__ void k_bias(const float* __restrict__ bih0, const float* __restrict__ bhh0,
                       const float* __restrict__ bih1, const float* __restrict__ bhh1,
                       float* __restrict__ bsum0, float* __restrict__ bsum1) {
  int i = blockIdx.x * blockDim.x + threadIdx.x;
  if (i < G4_) {
    bsum0[i] = bih0[i] + bhh0[i];
    bsum1[i] = bih1[i] + bhh1[i];
  }
}

// initial h: layer0 -> h0buf parity 0, layer1 -> h1buf parity 1
__global__ void k_init2(const float* __restrict__ h0,
                        u16* __restrict__ h0buf, u16* __restrict__ h1buf) {
  int i = blockIdx.x * blockDim.x + threadIdx.x;
  int n = B_ * H_;
  if (i < n) {
    bf16 a = __float2bfloat16(h0[i]);
    bf16 b = __float2bfloat16(h0[n + i]);
    h0buf[i] = *reinterpret_cast<u16*>(&a);          // parity 0
    h1buf[n + i] = *reinterpret_cast<u16*>(&b);      // parity 1
  }
}

__global__ void k_zero(int* p) {
  int i = blockIdx.x * blockDim.x + threadIdx.x;
  if (i < 256) p[i] = 0;
}

// ---------------- persistent LSTM kernel ----------------
// 256 WGs x 512 thr (8 waves -> 2 waves/SIMD). XCD-locality mapping:
//   lb = wg & 7 : layer = lb>>2, bg = lb&3 ; cg = wg >> 3 (0..31)
// WG owns batch rows [bg*128,+128) x h-cols [cg*16,+16).
// Waves: wave = rg*2 + kh. rg 0..3 owns rows [rg*32,+32) as M_rep=2 (two 16-row
// MFMA tiles); kh 0 = x-part (W_ih, K=512), kh 1 = h-part (W_hh, reset-masked).
// Each B-fragment ds_read feeds TWO MFMAs (M_rep=2): 512 b128/CU/phase (was 1024).
// Weights frag-blocked in LDS (conflict-free): block fb = ni*32 + kh*16 + s;
// lane l holds W[gate ni, col hbase+(l&15)][s*32 + (l>>4)*8 .. +7].
// K-split reduction: wave (rg,kh) finishes rows mi=kh. It writes acc[kh^1]
// (partial for partner's rows) into slot[partner]; after sync reads slot[self]
// and adds into acc[kh]. 16KB region, 2 rounds (waves 0-3 then 4-7), 3 syncs.
// Sync across WGs: per-WG flag slot (no RMW); wave 0 polls 64 domain slots in
// parallel. Cross-WG h via agent-scope relaxed atomics; no cache fences.
__global__ __launch_bounds__(512, 2)
void k_main(const u16* __restrict__ latb,
            const u16* __restrict__ W0i, const u16* __restrict__ W0h,
            const u16* __restrict__ W1i, const u16* __restrict__ W1h,
            const float* __restrict__ bs0, const float* __restrict__ bs1,
            const int* __restrict__ reset,   // (T,B)
            const float* __restrict__ c0,    // (2,B,H)
            u16* __restrict__ h0buf,         // [2][B][H]
            u16* __restrict__ h1buf,         // [2][B][H]
            float* __restrict__ hidden,      // (T,B,H)
            float* __restrict__ hn,          // (2,B,H)
            float* __restrict__ cn,          // (2,B,H)
            int* __restrict__ arr) {         // 256 flag slots, one per WG
  extern __shared__ char smem_raw[];
  u16*   wlds = (u16*)smem_raw;                 // 128KB frag-blocked weights
  float* xch  = (float*)(smem_raw + W_BYTES);   // 16KB exchange (4 slots x 4KB)
  __shared__ float hstage[8][16][20];           // per-wave h packing tile

  const int tid   = threadIdx.x;
  const int wg    = blockIdx.x;
  const int lb    = wg & 7;
  const int layer = lb >> 2;
  const int bg    = lb & 3;
  const int cg    = wg >> 3;
  const int hbase = cg * 16;
  const int rowbase = bg * 128;
  const int wave  = tid >> 6;                  // 0..7
  const int lane  = tid & 63;
  const int r16   = lane & 15;
  const int kq    = lane >> 4;                 // 0..3
  const int rg    = wave >> 1;                 // row-group 0..3 (32 rows each)
  const int kh    = wave & 1;                  // 0 = x-part, 1 = h-part
  const int wrow0 = rowbase + rg * 32;

  const u16* Wih = layer ? W1i : W0i;
  const u16* Whh = layer ? W1h : W0h;
  const float* bs = layer ? bs1 : bs0;
  u16* hself = layer ? h1buf : h0buf;

  // ---- stage weights into frag-blocked LDS (once) ----
  // chunk c = fb*64 + l ; fb = ni*32 + kslot ; kslot<16 -> W_ih, else W_hh
  for (int it = 0; it < 16; ++it) {
    int c = it * 512 + tid;                    // 0..8191
    int fb = c >> 6, l = c & 63;
    int ni = fb >> 5, kslot = fb & 31;
    int col = hbase + (l & 15);
    int klocal = (kslot & 15) * 32 + (l >> 4) * 8;
    const u16* M = (kslot < 16) ? Wih : Whh;
    const u16* src = M + (size_t)(ni * H_ + col) * K_ + klocal;
    *(float4*)(wlds + ((size_t)c) * 8) = *(const float4*)src;
  }

  // per-lane gate biases (col = hbase + r16)
  float bias[4];
  #pragma unroll
  for (int g = 0; g < 4; ++g) bias[g] = bs[g * H_ + hbase + r16];

  // c-state registers: j -> row = wrow0 + kh*16 + kq*4 + j (this wave's 16 rows)
  float creg[4];
  #pragma unroll
  for (int j = 0; j < 4; ++j)
    creg[j] = c0[((size_t)layer * B_ + (wrow0 + kh * 16 + kq * 4 + j)) * H_
                 + hbase + r16];

  __syncthreads();

  for (int p = 0; p <= T_; ++p) {
    const int t = layer ? (p - 1) : p;
    const bool active = (t >= 0 && t < T_);
    float hnew_r[4], cnew_r[4];

    if (active) {
      const u16* X  = layer ? (h0buf + (size_t)(p & 1) * B_ * H_)
                            : (latb + (size_t)t * B_ * K_);
      const u16* Hp = hself + (size_t)(p & 1) * B_ * H_;
      u16* Hn       = hself + (size_t)((p + 1) & 1) * B_ * H_;
      const int* rst_t = reset + (size_t)t * B_;

      // A source for this wave's K-half; rows r16 and r16+16 of its 32-row group
      const u16* Abase = kh ? Hp : X;
      const u16* a0p = Abase + (size_t)(wrow0 + r16) * 512 + kq * 8;
      const u16* a1p = Abase + (size_t)(wrow0 + 16 + r16) * 512 + kq * 8;
      const int ra0 = kh ? rst_t[wrow0 + r16] : 0;
      const int ra1 = kh ? rst_t[wrow0 + 16 + r16] : 0;

      f32x4 acc[2][4] = {};
      const frag zf = {};

#define KLOOP(LOAD0, LOAD1)                                                   \
      _Pragma("unroll")                                                       \
      for (int s = 0; s < 16; ++s) {                                          \
        frag a0 = (LOAD0);                                                    \
        frag a1 = (LOAD1);                                                    \
        _Pragma("unroll")                                                     \
        for (int ni = 0; ni < 4; ++ni) {                                      \
          frag b = *reinterpret_cast<const frag*>(                            \
              wlds + ((size_t)((ni * 32 + kh * 16 + s) * 64 + lane)) * 8);    \
          acc[0][ni] = __builtin_amdgcn_mfma_f32_16x16x32_bf16(a0, b, acc[0][ni], 0, 0, 0); \
          acc[1][ni] = __builtin_amdgcn_mfma_f32_16x16x32_bf16(a1, b, acc[1][ni], 0, 0, 0); \
        }                                                                     \
      }

      if (kh == 0) {
        if (layer == 0) {
          KLOOP(*reinterpret_cast<const frag*>(a0p + s * 32),
                *reinterpret_cast<const frag*>(a1p + s * 32))
        } else {
          KLOOP(ld_coh(a0p + s * 32), ld_coh(a1p + s * 32))
        }
      } else {
        KLOOP(ra0 ? zf : ld_coh(a0p + s * 32),
              ra1 ? zf : ld_coh(a1p + s * 32))
      }
#undef KLOOP

      // ---- K-half reduction: symmetric partner exchange, 2 rounds ----
      // slot sw (0..3) at xch + sw*1024 floats; layout ni*256 + lane*4 (f32x4).
      // Wave w writes acc[kh^1] (partial for partner's rows) to slot[(w^1)&3].
      const int swW = (wave ^ 1) & 3;      // write slot (partner's id in region)
      const int swR = wave & 3;            // read slot (own id in region)
      if (wave < 4) {
        #pragma unroll
        for (int ni = 0; ni < 4; ++ni)
          *(f32x4*)(xch + (size_t)swW * 1024 + ni * 256 + lane * 4) = acc[kh ^ 1][ni];
      }
      __syncthreads();                     // sync1: round-A writes visible
      if (wave < 4) {
        #pragma unroll
        for (int ni = 0; ni < 4; ++ni)
          acc[kh][ni] += *(const f32x4*)(xch + (size_t)swR * 1024 + ni * 256 + lane * 4);
      }
      __syncthreads();                     // sync2: round-A reads done
      if (wave >= 4) {
        #pragma unroll
        for (int ni = 0; ni < 4; ++ni)
          *(f32x4*)(xch + (size_t)swW * 1024 + ni * 256 + lane * 4) = acc[kh ^ 1][ni];
      }
      __syncthreads();                     // sync3: round-B writes visible
      if (wave >= 4) {
        #pragma unroll
        for (int ni = 0; ni < 4; ++ni)
          acc[kh][ni] += *(const f32x4*)(xch + (size_t)swR * 1024 + ni * 256 + lane * 4);
      }

      // ---- cell elementwise: this wave's 16 rows (mi = kh) ----
      #pragma unroll
      for (int j = 0; j < 4; ++j) {
        const int row = wrow0 + kh * 16 + kq * 4 + j;
        const int rstj = rst_t[row];
        float gi = acc[kh][0][j] + bias[0];
        float gf = acc[kh][1][j] + bias[1];
        float gg = acc[kh][2][j] + bias[2];
        float go = acc[kh][3][j] + bias[3];
        float iv = 1.f / (1.f + __expf(-gi));
        float fv = 1.f / (1.f + __expf(-gf));
        float gv = 1.f - 2.f / (__expf(2.f * gg) + 1.f);   // tanh
        float ov = 1.f / (1.f + __expf(-go));
        float ce = rstj ? 0.f : creg[j];
        float cnew = fv * ce + iv * gv;
        float hnew = ov * (1.f - 2.f / (__expf(2.f * cnew) + 1.f));
        creg[j] = cnew;
        cnew_r[j] = cnew;
        hnew_r[j] = hnew;
        hstage[wave][kq * 4 + j][r16] = hnew;   // wave-local LDS (in-wave order)
      }

      // pack + coherent h stores: lane -> (row = lane>>2, 4 cols at (lane&3)*4)
      {
        const int prow = lane >> 2;
        const int pc4  = lane & 3;
        float4 v = *reinterpret_cast<const float4*>(&hstage[wave][prow][pc4 * 4]);
        bf16 b0 = __float2bfloat16(v.x), b1 = __float2bfloat16(v.y);
        bf16 b2 = __float2bfloat16(v.z), b3 = __float2bfloat16(v.w);
        u64 pk = (u64)*reinterpret_cast<u16*>(&b0)
               | ((u64)*reinterpret_cast<u16*>(&b1) << 16)
               | ((u64)*reinterpret_cast<u16*>(&b2) << 32)
               | ((u64)*reinterpret_cast<u16*>(&b3) << 48);
        u16* dst = Hn + (size_t)(wrow0 + kh * 16 + prow) * H_ + hbase + pc4 * 4;
        __hip_atomic_store((u64*)dst, pk, __ATOMIC_RELAXED, __HIP_MEMORY_SCOPE_AGENT);
      }
    }

    // barrier arrival: own-slot flag store (no RMW), after h stores acked
    if (p < T_) {
      asm volatile("s_waitcnt vmcnt(0)" ::: "memory");
      __syncthreads();
      if (tid == 0)
        __hip_atomic_store(arr + wg, p + 1, __ATOMIC_RELAXED, __HIP_MEMORY_SCOPE_AGENT);
    }

    // deferred output stores (overlap with poll; nobody reads these in-kernel)
    if (active) {
      float* hidden_t = hidden + (size_t)t * B_ * H_;
      #pragma unroll
      for (int j = 0; j < 4; ++j) {
        const size_t off = (size_t)(wrow0 + kh * 16 + kq * 4 + j) * H_ + hbase + r16;
        if (layer) hidden_t[off] = hnew_r[j];
        if (t == T_ - 1) {
          hn[(size_t)layer * B_ * H_ + off] = hnew_r[j];
          cn[(size_t)layer * B_ * H_ + off] = cnew_r[j];
        }
      }
    }

    // barrier wait: wave 0's 64 lanes poll the 64 pair-domain slots in parallel
    if (p < T_) {
      if (wave == 0) {
        const int slot = (lane >> 1) * 8 + (lane & 1) * 4 + bg;  // all 64 domain WGs
        while (__hip_atomic_load(arr + slot, __ATOMIC_RELAXED,
                                 __HIP_MEMORY_SCOPE_AGENT) < p + 1)
          __builtin_amdgcn_s_sleep(2);
      }
      __syncthreads();
    }
  }
}

// ---------------- host ----------------

extern "C" void kernel_launch(void* const* d_in, const int* in_sizes, int n_in,
                              void* d_out, int out_size, void* d_ws, size_t ws_size,
                              hipStream_t stream) {
  (void)in_sizes; (void)n_in; (void)out_size; (void)ws_size;

  const float* latent = (const float*)d_in[0];
  const float* h0in   = (const float*)d_in[1];
  const float* c0in   = (const float*)d_in[2];
  const int*   reset  = (const int*)d_in[3];
  const float* W_ih0  = (const float*)d_in[4];
  const float* W_hh0  = (const float*)d_in[5];
  const float* b_ih0  = (const float*)d_in[6];
  const float* b_hh0  = (const float*)d_in[7];
  const float* W_ih1  = (const float*)d_in[8];
  const float* W_hh1  = (const float*)d_in[9];
  const float* b_ih1  = (const float*)d_in[10];
  const float* b_hh1  = (const float*)d_in[11];

  float* out    = (float*)d_out;
  float* hidden = out;                               // (T,B,H)
  float* hn     = out + (size_t)T_ * B_ * H_;        // (2,B,H)
  float* cn     = hn + (size_t)2 * B_ * H_;          // (2,B,H)

  // workspace layout
  char* ws = (char*)d_ws;
  u16* latb  = (u16*)ws;                             // T*B*K bf16 (64 MiB)
  u16* wih0b = latb + (size_t)T_ * B_ * K_;
  u16* whh0b = wih0b + (size_t)G4_ * K_;
  u16* wih1b = whh0b + (size_t)G4_ * K_;
  u16* whh1b = wih1b + (size_t)G4_ * K_;
  float* bsum0 = (float*)(whh1b + (size_t)G4_ * K_);
  float* bsum1 = bsum0 + G4_;
  u16* h0buf = (u16*)(bsum1 + G4_);                  // [2][B][H]
  u16* h1buf = h0buf + (size_t)2 * B_ * H_;
  int* arr   = (int*)(h1buf + (size_t)2 * B_ * H_);  // 256 flag slots

  // conversions / init (stream-ordered)
  int n_lat4 = T_ * B_ * K_ / 4;
  k_f32_to_bf16_v4<<<2048, 256, 0, stream>>>((const float4*)latent, (ushort4*)latb, n_lat4);
  int n_w4 = G4_ * K_ / 4;
  k_f32_to_bf16_v4<<<256, 256, 0, stream>>>((const float4*)W_ih0, (ushort4*)wih0b, n_w4);
  k_f32_to_bf16_v4<<<256, 256, 0, stream>>>((const float4*)W_hh0, (ushort4*)whh0b, n_w4);
  k_f32_to_bf16_v4<<<256, 256, 0, stream>>>((const float4*)W_ih1, (ushort4*)wih1b, n_w4);
  k_f32_to_bf16_v4<<<256, 256, 0, stream>>>((const float4*)W_hh1, (ushort4*)whh1b, n_w4);
  k_bias<<<(G4_ + 255) / 256, 256, 0, stream>>>(b_ih0, b_hh0, b_ih1, b_hh1, bsum0, bsum1);
  k_init2<<<(B_ * H_ + 255) / 256, 256, 0, stream>>>(h0in, h0buf, h1buf);
  k_zero<<<1, 256, 0, stream>>>(arr);

  // persistent cooperative kernel
  hipFuncSetAttribute((const void*)k_main, hipFuncAttributeMaxDynamicSharedMemorySize,
                      (int)SMEM_BYTES);
  void* args[] = { (void*)&latb, (void*)&wih0b, (void*)&whh0b, (void*)&wih1b, (void*)&whh1b,
                   (void*)&bsum0, (void*)&bsum1, (void*)&reset, (void*)&c0in,
                   (void*)&h0buf, (void*)&h1buf, (void*)&hidden, (void*)&hn, (void*)&cn,
                   (void*)&arr };
  hipLaunchCooperativeKernel((void*)k_main, dim3(NWG), dim3(512), args,
                             (unsigned int)SMEM_BYTES, stream);
}

// Round 12
// 1563.058 us; speedup vs baseline: 2.3290x; 2.3290x over previous
//
#include <hip/hip_runtime.h>
#include <hip/hip_bf16.h>

typedef __hip_bfloat16 bf16;
typedef unsigned short u16;
typedef unsigned long long u64;
using frag  = __attribute__((ext_vector_type(8))) short;   // 8 bf16
using f32x4 = __attribute__((ext_vector_type(4))) float;   // 4 fp32 acc

static constexpr int T_  = 128;
static constexpr int B_  = 512;
static constexpr int H_  = 512;
static constexpr int K_  = 512;
static constexpr int G4_ = 2048;
static constexpr int NWG = 256;

// dynamic LDS: frag-blocked weights only (128 blocks x 1KB)
static constexpr size_t W_BYTES = 131072;
static constexpr size_t SMEM_BYTES = W_BYTES;

// coherent (agent-scope, L1/L2-bypassing) 16B load as 2x b64 relaxed atomics
// used ONLY for the cross-XCD layer0->layer1 h0 handoff
__device__ __forceinline__ frag ld_coh(const u16* p) {
  u64 lo = __hip_atomic_load((const u64*)p,       __ATOMIC_RELAXED, __HIP_MEMORY_SCOPE_AGENT);
  u64 hi = __hip_atomic_load((const u64*)(p + 4), __ATOMIC_RELAXED, __HIP_MEMORY_SCOPE_AGENT);
  union { u64 q[2]; frag f; } u;
  u.q[0] = lo; u.q[1] = hi;
  return u.f;
}

// ---------------- setup kernels ----------------

__global__ void k_f32_to_bf16_v4(const float4* __restrict__ src,
                                 ushort4* __restrict__ dst, int n4) {
  int i = blockIdx.x * blockDim.x + threadIdx.x;
  int stride = gridDim.x * blockDim.x;
  for (; i < n4; i += stride) {
    float4 v = src[i];
    ushort4 o;
    bf16 t0 = __float2bfloat16(v.x); o.x = *reinterpret_cast<u16*>(&t0);
    bf16 t1 = __float2bfloat16(v.y); o.y = *reinterpret_cast<u16*>(&t1);
    bf16 t2 = __float2bfloat16(v.z); o.z = *reinterpret_cast<u16*>(&t2);
    bf16 t3 = __float2bfloat16(v.w); o.w = *reinterpret_cast<u16*>(&t3);
    dst[i] = o;
  }
}

__global__ void k_bias(const float* __restrict__ bih0, const float* __restrict__ bhh0,
                       const float* __restrict__ bih1, const float* __restrict__ bhh1,
                       float* __restrict__ bsum0, float* __restrict__ bsum1) {
  int i = blockIdx.x * blockDim.x + threadIdx.x;
  if (i < G4_) {
    bsum0[i] = bih0[i] + bhh0[i];
    bsum1[i] = bih1[i] + bhh1[i];
  }
}

// initial h into the per-layer L2-local buffers (kernel-end flush makes these
// visible to k_main's clean-cache first reads): layer0 -> bufA0 parity 0,
// layer1 -> bufA1 parity 1.
__global__ void k_init2(const float* __restrict__ h0,
                        u16* __restrict__ bufA0, u16* __restrict__ bufA1) {
  int i = blockIdx.x * blockDim.x + threadIdx.x;
  int n = B_ * H_;
  if (i < n) {
    bf16 a = __float2bfloat16(h0[i]);
    bf16 b = __float2bfloat16(h0[n + i]);
    bufA0[i] = *reinterpret_cast<u16*>(&a);          // parity 0
    bufA1[n + i] = *reinterpret_cast<u16*>(&b);      // parity 1
  }
}

__global__ void k_zero(int* p) {
  int i = blockIdx.x * blockDim.x + threadIdx.x;
  if (i < 256) p[i] = 0;
}

// ---------------- persistent LSTM kernel ----------------
// 256 WGs x 512 thr (8 waves -> 2 waves/SIMD). XCD-locality mapping:
//   lb = wg & 7 : layer = lb>>2, bg = lb&3 ; cg = wg >> 3 (0..31)
// WG owns batch rows [bg*128,+128) x h-cols [cg*16,+16); wave w owns rows
// [bg*128 + w*16, +16), all 4 gates. (R10 structure.)
// Weights in LDS, FRAG-BLOCKED (conflict-free ds_read_b128).
// h data paths:
//   h-self: bufA{layer} — PLAIN stores (drain to the XCD's L2 before the flag)
//     and PLAIN loads. L1 staleness killed by one `buffer_inv sc0` (L1-only
//     invalidate) per wave per phase, right after the barrier. Writer and all
//     readers share the XCD by the wg-mapping, so L2 is the coherence point.
//   layer0 -> layer1 x handoff: layer0 dual-stores h0 (plain -> bufA0, agent
//     atomic -> h0buf/L3); layer1 reads h0buf via ld_coh (bypass, no staleness).
// Sync: per-WG flag slot (no RMW); wave 0 polls 64 domain slots in parallel.
// c-state in regs; hidden/hn/cn stores deferred past flag store.
__global__ __launch_bounds__(512, 2)
void k_main(const u16* __restrict__ latb,
            const u16* __restrict__ W0i, const u16* __restrict__ W0h,
            const u16* __restrict__ W1i, const u16* __restrict__ W1h,
            const float* __restrict__ bs0, const float* __restrict__ bs1,
            const int* __restrict__ reset,   // (T,B)
            const float* __restrict__ c0,    // (2,B,H)
            u16* __restrict__ h0buf,         // [2][B][H] coherent cross-layer h0
            u16* __restrict__ bufA0,         // [2][B][H] layer0 h-self (L2-local)
            u16* __restrict__ bufA1,         // [2][B][H] layer1 h-self (L2-local)
            float* __restrict__ hidden,      // (T,B,H)
            float* __restrict__ hn,          // (2,B,H)
            float* __restrict__ cn,          // (2,B,H)
            int* __restrict__ arr) {         // 256 flag slots, one per WG
  extern __shared__ char smem_raw[];
  u16* wlds = (u16*)smem_raw;                // 128KB frag-blocked weights
  __shared__ float hstage[8][16][20];        // per-wave h packing tile

  const int tid   = threadIdx.x;
  const int wg    = blockIdx.x;
  const int lb    = wg & 7;
  const int layer = lb >> 2;
  const int bg    = lb & 3;
  const int cg    = wg >> 3;
  const int hbase = cg * 16;
  const int rowbase = bg * 128;
  const int wave  = tid >> 6;                  // 0..7
  const int lane  = tid & 63;
  const int r16   = lane & 15;
  const int kq    = lane >> 4;                 // 0..3
  const int wrow_local = wave * 16;            // wave's batch offset within WG
  const int wrow0 = rowbase + wrow_local;

  const u16* Wih = layer ? W1i : W0i;
  const u16* Whh = layer ? W1h : W0h;
  const float* bs = layer ? bs1 : bs0;
  u16* bufA_self = layer ? bufA1 : bufA0;

  // ---- stage weights into frag-blocked LDS (once) ----
  // chunk c = fb*64 + l ; fb = ni*32 + kslot ; kslot<16 -> W_ih, else W_hh
  for (int it = 0; it < 16; ++it) {
    int c = it * 512 + tid;                    // 0..8191
    int fb = c >> 6, l = c & 63;
    int ni = fb >> 5, kslot = fb & 31;
    int col = hbase + (l & 15);
    int klocal = (kslot & 15) * 32 + (l >> 4) * 8;
    const u16* M = (kslot < 16) ? Wih : Whh;
    const u16* src = M + (size_t)(ni * H_ + col) * K_ + klocal;
    *(float4*)(wlds + ((size_t)c) * 8) = *(const float4*)src;
  }

  // per-lane gate biases (col = hbase + r16)
  float bias[4];
  #pragma unroll
  for (int g = 0; g < 4; ++g) bias[g] = bs[g * H_ + hbase + r16];

  // c-state registers: j -> row = wrow0 + kq*4 + j, col = hbase + r16
  float creg[4];
  #pragma unroll
  for (int j = 0; j < 4; ++j)
    creg[j] = c0[((size_t)layer * B_ + (wrow0 + kq * 4 + j)) * H_ + hbase + r16];

  __syncthreads();

  for (int p = 0; p <= T_; ++p) {
    // L1-only invalidate: h-self lines written by sibling CUs last phase must
    // not be served from stale L1. L2 (same XCD) is current. After-barrier
    // placement guarantees all writers have drained to L2.
    if (p) { asm volatile("buffer_inv sc0" ::: "memory"); }

    const int t = layer ? (p - 1) : p;
    const bool active = (t >= 0 && t < T_);
    float hnew_r[4], cnew_r[4];

    if (active) {
      const u16* X  = layer ? (h0buf + (size_t)(p & 1) * B_ * H_)
                            : (latb + (size_t)t * B_ * K_);
      const u16* Hp = bufA_self + (size_t)(p & 1) * B_ * H_;
      u16* HnA      = bufA_self + (size_t)((p + 1) & 1) * B_ * H_;
      u16* Hn0c     = h0buf + (size_t)((p + 1) & 1) * B_ * H_;   // layer0 only

      const int* rst_t = reset + (size_t)t * B_;
      const int ra0 = rst_t[wrow0 + r16];           // mask for this lane's A row
      const u16* x0  = X  + (size_t)(wrow0 + r16) * K_ + kq * 8;
      const u16* hp0 = Hp + (size_t)(wrow0 + r16) * H_ + kq * 8;

      f32x4 acc[4] = {};
      const frag zf = {};

      // merged x+h K-loop, in-loop loads (compiler-scheduled), frag-blocked B
      if (layer == 0) {
        #pragma unroll
        for (int s = 0; s < 16; ++s) {
          frag a  = *reinterpret_cast<const frag*>(x0 + s * 32);
          frag ah = ra0 ? zf : *reinterpret_cast<const frag*>(hp0 + s * 32);
          #pragma unroll
          for (int ni = 0; ni < 4; ++ni) {
            frag bx = *reinterpret_cast<const frag*>(
                wlds + ((size_t)((ni * 32 + s) * 64 + lane)) * 8);
            frag bh = *reinterpret_cast<const frag*>(
                wlds + ((size_t)((ni * 32 + 16 + s) * 64 + lane)) * 8);
            acc[ni] = __builtin_amdgcn_mfma_f32_16x16x32_bf16(a,  bx, acc[ni], 0, 0, 0);
            acc[ni] = __builtin_amdgcn_mfma_f32_16x16x32_bf16(ah, bh, acc[ni], 0, 0, 0);
          }
        }
      } else {
        #pragma unroll
        for (int s = 0; s < 16; ++s) {
          frag a  = ld_coh(x0 + s * 32);
          frag ah = ra0 ? zf : *reinterpret_cast<const frag*>(hp0 + s * 32);
          #pragma unroll
          for (int ni = 0; ni < 4; ++ni) {
            frag bx = *reinterpret_cast<const frag*>(
                wlds + ((size_t)((ni * 32 + s) * 64 + lane)) * 8);
            frag bh = *reinterpret_cast<const frag*>(
                wlds + ((size_t)((ni * 32 + 16 + s) * 64 + lane)) * 8);
            acc[ni] = __builtin_amdgcn_mfma_f32_16x16x32_bf16(a,  bx, acc[ni], 0, 0, 0);
            acc[ni] = __builtin_amdgcn_mfma_f32_16x16x32_bf16(ah, bh, acc[ni], 0, 0, 0);
          }
        }
      }

      // cell elementwise: lane-local (4 outputs: rows kq*4+j, col r16)
      #pragma unroll
      for (int j = 0; j < 4; ++j) {
        const int rstj = rst_t[wrow0 + kq * 4 + j];
        float gi = acc[0][j] + bias[0];
        float gf = acc[1][j] + bias[1];
        float gg = acc[2][j] + bias[2];
        float go = acc[3][j] + bias[3];
        float iv = 1.f / (1.f + __expf(-gi));
        float fv = 1.f / (1.f + __expf(-gf));
        float gv = 1.f - 2.f / (__expf(2.f * gg) + 1.f);   // tanh
        float ov = 1.f / (1.f + __expf(-go));
        float ce = rstj ? 0.f : creg[j];
        float cnew = fv * ce + iv * gv;
        float hnew = ov * (1.f - 2.f / (__expf(2.f * cnew) + 1.f));
        creg[j] = cnew;
        cnew_r[j] = cnew;
        hnew_r[j] = hnew;
        hstage[wave][kq * 4 + j][r16] = hnew;   // wave-local LDS (in-wave order)
      }

      // pack + h stores: lane -> (row = lane>>2, 4 cols at (lane&3)*4)
      {
        const int prow = lane >> 2;
        const int pc4  = lane & 3;
        float4 v = *reinterpret_cast<const float4*>(&hstage[wave][prow][pc4 * 4]);
        bf16 b0 = __float2bfloat16(v.x), b1 = __float2bfloat16(v.y);
        bf16 b2 = __float2bfloat16(v.z), b3 = __float2bfloat16(v.w);
        u64 pk = (u64)*reinterpret_cast<u16*>(&b0)
               | ((u64)*reinterpret_cast<u16*>(&b1) << 16)
               | ((u64)*reinterpret_cast<u16*>(&b2) << 32)
               | ((u64)*reinterpret_cast<u16*>(&b3) << 48);
        const size_t hoff = (size_t)(wrow0 + prow) * H_ + hbase + pc4 * 4;
        *(u64*)(HnA + hoff) = pk;                       // plain -> local L2
        if (layer == 0) {
          __hip_atomic_store((u64*)(Hn0c + hoff), pk,
                             __ATOMIC_RELAXED, __HIP_MEMORY_SCOPE_AGENT);  // -> L3
        }
      }
    }

    // barrier arrival: own-slot flag store (no RMW), after h stores acked
    if (p < T_) {
      asm volatile("s_waitcnt vmcnt(0)" ::: "memory");
      __syncthreads();
      if (tid == 0)
        __hip_atomic_store(arr + wg, p + 1, __ATOMIC_RELAXED, __HIP_MEMORY_SCOPE_AGENT);
    }

    // deferred output stores (overlap with poll; nobody reads these in-kernel)
    if (active) {
      float* hidden_t = hidden + (size_t)t * B_ * H_;
      #pragma unroll
      for (int j = 0; j < 4; ++j) {
        const size_t off = (size_t)(wrow0 + kq * 4 + j) * H_ + hbase + r16;
        if (layer) hidden_t[off] = hnew_r[j];
        if (t == T_ - 1) {
          hn[(size_t)layer * B_ * H_ + off] = hnew_r[j];
          cn[(size_t)layer * B_ * H_ + off] = cnew_r[j];
        }
      }
    }

    // barrier wait: wave 0's 64 lanes poll the 64 pair-domain slots in parallel
    if (p < T_) {
      if (wave == 0) {
        const int slot = (lane >> 1) * 8 + (lane & 1) * 4 + bg;  // all 64 domain WGs
        while (__hip_atomic_load(arr + slot, __ATOMIC_RELAXED,
                                 __HIP_MEMORY_SCOPE_AGENT) < p + 1)
          __builtin_amdgcn_s_sleep(2);
      }
      __syncthreads();
    }
  }
}

// ---------------- host ----------------

extern "C" void kernel_launch(void* const* d_in, const int* in_sizes, int n_in,
                              void* d_out, int out_size, void* d_ws, size_t ws_size,
                              hipStream_t stream) {
  (void)in_sizes; (void)n_in; (void)out_size; (void)ws_size;

  const float* latent = (const float*)d_in[0];
  const float* h0in   = (const float*)d_in[1];
  const float* c0in   = (const float*)d_in[2];
  const int*   reset  = (const int*)d_in[3];
  const float* W_ih0  = (const float*)d_in[4];
  const float* W_hh0  = (const float*)d_in[5];
  const float* b_ih0  = (const float*)d_in[6];
  const float* b_hh0  = (const float*)d_in[7];
  const float* W_ih1  = (const float*)d_in[8];
  const float* W_hh1  = (const float*)d_in[9];
  const float* b_ih1  = (const float*)d_in[10];
  const float* b_hh1  = (const float*)d_in[11];

  float* out    = (float*)d_out;
  float* hidden = out;                               // (T,B,H)
  float* hn     = out + (size_t)T_ * B_ * H_;        // (2,B,H)
  float* cn     = hn + (size_t)2 * B_ * H_;          // (2,B,H)

  // workspace layout
  char* ws = (char*)d_ws;
  u16* latb  = (u16*)ws;                             // T*B*K bf16 (64 MiB)
  u16* wih0b = latb + (size_t)T_ * B_ * K_;
  u16* whh0b = wih0b + (size_t)G4_ * K_;
  u16* wih1b = whh0b + (size_t)G4_ * K_;
  u16* whh1b = wih1b + (size_t)G4_ * K_;
  float* bsum0 = (float*)(whh1b + (size_t)G4_ * K_);
  float* bsum1 = bsum0 + G4_;
  u16* h0buf = (u16*)(bsum1 + G4_);                  // [2][B][H] coherent
  u16* bufA0 = h0buf + (size_t)2 * B_ * H_;          // [2][B][H] L2-local
  u16* bufA1 = bufA0 + (size_t)2 * B_ * H_;          // [2][B][H] L2-local
  int* arr   = (int*)(bufA1 + (size_t)2 * B_ * H_);  // 256 flag slots

  // conversions / init (stream-ordered)
  int n_lat4 = T_ * B_ * K_ / 4;
  k_f32_to_bf16_v4<<<2048, 256, 0, stream>>>((const float4*)latent, (ushort4*)latb, n_lat4);
  int n_w4 = G4_ * K_ / 4;
  k_f32_to_bf16_v4<<<256, 256, 0, stream>>>((const float4*)W_ih0, (ushort4*)wih0b, n_w4);
  k_f32_to_bf16_v4<<<256, 256, 0, stream>>>((const float4*)W_hh0, (ushort4*)whh0b, n_w4);
  k_f32_to_bf16_v4<<<256, 256, 0, stream>>>((const float4*)W_ih1, (ushort4*)wih1b, n_w4);
  k_f32_to_bf16_v4<<<256, 256, 0, stream>>>((const float4*)W_hh1, (ushort4*)whh1b, n_w4);
  k_bias<<<(G4_ + 255) / 256, 256, 0, stream>>>(b_ih0, b_hh0, b_ih1, b_hh1, bsum0, bsum1);
  k_init2<<<(B_ * H_ + 255) / 256, 256, 0, stream>>>(h0in, bufA0, bufA1);
  k_zero<<<1, 256, 0, stream>>>(arr);

  // persistent cooperative kernel
  hipFuncSetAttribute((const void*)k_main, hipFuncAttributeMaxDynamicSharedMemorySize,
                      (int)SMEM_BYTES);
  void* args[] = { (void*)&latb, (void*)&wih0b, (void*)&whh0b, (void*)&wih1b, (void*)&whh1b,
                   (void*)&bsum0, (void*)&bsum1, (void*)&reset, (void*)&c0in,
                   (void*)&h0buf, (void*)&bufA0, (void*)&bufA1,
                   (void*)&hidden, (void*)&hn, (void*)&cn, (void*)&arr };
  hipLaunchCooperativeKernel((void*)k_main, dim3(NWG), dim3(512), args,
                             (unsigned int)SMEM_BYTES, stream);
}